// Round 4
// baseline (128.743 us; speedup 1.0000x reference)
//
#include <hip/hip_runtime.h>

#define SS 160
#define DD 256
#define BB 8
#define NPAIR 12720            // S*(S-1)/2
#define M_TOT (BB * SS)        // 1280
#define TOTROWS (BB * NPAIR)   // 101760
#define NWAVES 8192            // 2048 blocks x 4 waves = 8 waves/SIMD device-wide

// ---------------------------------------------------------------------------
// Kernel 1 (UNCHANGED from R3): fused double GEMM. BM=32, BN=64, BK=32 ->
// grid (8,40)=320 blocks. Each thread: 2 rows x 4 cols.
//   ya[m][e] = x[m][:] @ W[:256][e] + bias[e]
//   yb[m][e] = x[m][:] @ W[256:][e]
// ---------------------------------------------------------------------------
__global__ __launch_bounds__(256) void gemm_kernel(const float* __restrict__ x,
                                                   const float* __restrict__ W,
                                                   const float* __restrict__ bias,
                                                   float* __restrict__ y) {
    const int BM = 32, BN = 64, BK = 32;
    __shared__ float As[BK][BM + 1];   // transposed: As[k][m], +1 pad
    __shared__ float Bs[BK][BN];

    const int n0 = blockIdx.x * BN;
    const int m0 = blockIdx.y * BM;
    const int half = (n0 >= DD) ? 1 : 0;
    const float* Wbase = W + (half ? DD * DD : 0);
    const int ncol0 = n0 - (half ? DD : 0);

    const int tid = threadIdx.x;
    const int tx = tid & 15;
    const int ty = tid >> 4;

    const int ar = tid >> 3;
    const int ac = (tid & 7) << 2;
    const int bkr = tid >> 4;
    const int bnc = (tid & 15) << 2;

    float acc0[4] = {0.f, 0.f, 0.f, 0.f};
    float acc1[4] = {0.f, 0.f, 0.f, 0.f};

    for (int k0 = 0; k0 < DD; k0 += BK) {
        float4 av = *(const float4*)(x + (m0 + ar) * DD + k0 + ac);
        float4 b0 = *(const float4*)(Wbase + (k0 + bkr) * DD + ncol0 + bnc);
        float4 b1 = *(const float4*)(Wbase + (k0 + bkr + 16) * DD + ncol0 + bnc);
        __syncthreads();
        As[ac + 0][ar] = av.x;
        As[ac + 1][ar] = av.y;
        As[ac + 2][ar] = av.z;
        As[ac + 3][ar] = av.w;
        *(float4*)(&Bs[bkr][bnc])      = b0;
        *(float4*)(&Bs[bkr + 16][bnc]) = b1;
        __syncthreads();
#pragma unroll
        for (int kk = 0; kk < BK; ++kk) {
            float a0 = As[kk][ty];
            float a1 = As[kk][ty + 16];
            float4 bv = *(const float4*)(&Bs[kk][tx << 2]);
            acc0[0] += a0 * bv.x; acc0[1] += a0 * bv.y;
            acc0[2] += a0 * bv.z; acc0[3] += a0 * bv.w;
            acc1[0] += a1 * bv.x; acc1[1] += a1 * bv.y;
            acc1[2] += a1 * bv.z; acc1[3] += a1 * bv.w;
        }
    }

    float4 bias4 = make_float4(0.f, 0.f, 0.f, 0.f);
    if (!half) bias4 = *(const float4*)(bias + ncol0 + (tx << 2));

    float* yout = y + (half ? M_TOT * DD : 0);
    float4 r0, r1;
    r0.x = acc0[0] + bias4.x; r0.y = acc0[1] + bias4.y;
    r0.z = acc0[2] + bias4.z; r0.w = acc0[3] + bias4.w;
    r1.x = acc1[0] + bias4.x; r1.y = acc1[1] + bias4.y;
    r1.z = acc1[2] + bias4.z; r1.w = acc1[3] + bias4.w;
    *(float4*)(yout + (m0 + ty) * DD + ncol0 + (tx << 2))      = r0;
    *(float4*)(yout + (m0 + ty + 16) * DD + ncol0 + (tx << 2)) = r1;
}

// ---------------------------------------------------------------------------
// Kernel 2 (v4): balanced pair expansion, run-decomposed + 4x unrolled.
// Each wave's contiguous row slice is processed as runs of consecutive j
// (branch-free inner body, 4 independent loads in flight, 4 KB stores per
// unrolled iter). va reloaded only at run boundaries (i-change).
// ---------------------------------------------------------------------------
__global__ __launch_bounds__(256) void expand_kernel(const float* __restrict__ y,
                                                     float* __restrict__ out) {
    const int gw   = (blockIdx.x << 2) + (threadIdx.x >> 6);   // 0..NWAVES-1
    const int lane = threadIdx.x & 63;

    int r0 = (int)(((long long)gw * TOTROWS) / NWAVES);
    int r1 = (int)(((long long)(gw + 1) * TOTROWS) / NWAVES);

    int b = (unsigned)r0 / NPAIR;
    int p = r0 - b * NPAIR;

    // invert p -> (i,j): offset(i) = i*(2S-1-i)/2, j = i+1 + (p - offset(i))
    float disc = sqrtf((float)(101761 - 8 * p));     // (2S-1)^2 = 101761
    int i = (int)((319.0f - disc) * 0.5f);
    if (i < 0) i = 0;
    if (i > SS - 2) i = SS - 2;
    while (i > 0 && (i * (2 * SS - 1 - i)) / 2 > p) --i;
    while (((i + 1) * (2 * SS - 2 - i)) / 2 <= p) ++i;
    int j = i + 1 + p - (i * (2 * SS - 1 - i)) / 2;

    const float4* ya4 = (const float4*)y;
    const float4* yb4 = (const float4*)(y + M_TOT * DD);
    float4* po = (float4*)out + ((long long)r0 << 6) + lane;

    int r = r0;
    while (r < r1) {
        int run = r1 - r;
        int jrem = SS - j;
        if (jrem < run) run = jrem;                 // rows with consecutive j

        const float4 va = ya4[((b * SS + i) << 6) + lane];
        const float4* pb = yb4 + ((b * SS + j) << 6) + lane;

        int k = 0;
        for (; k + 4 <= run; k += 4) {              // 4 loads in flight
            float4 v0 = pb[0];
            float4 v1 = pb[64];
            float4 v2 = pb[128];
            float4 v3 = pb[192];
            float4 o0, o1, o2, o3;
            o0.x = va.x + v0.x; o0.y = va.y + v0.y; o0.z = va.z + v0.z; o0.w = va.w + v0.w;
            o1.x = va.x + v1.x; o1.y = va.y + v1.y; o1.z = va.z + v1.z; o1.w = va.w + v1.w;
            o2.x = va.x + v2.x; o2.y = va.y + v2.y; o2.z = va.z + v2.z; o2.w = va.w + v2.w;
            o3.x = va.x + v3.x; o3.y = va.y + v3.y; o3.z = va.z + v3.z; o3.w = va.w + v3.w;
            po[0]   = o0;
            po[64]  = o1;
            po[128] = o2;
            po[192] = o3;
            pb += 256;
            po += 256;
        }
        for (; k < run; ++k) {
            float4 vb = *pb;
            float4 o;
            o.x = va.x + vb.x; o.y = va.y + vb.y;
            o.z = va.z + vb.z; o.w = va.w + vb.w;
            *po = o;
            pb += 64;
            po += 64;
        }

        r += run;
        j += run;
        if (j == SS) {                              // advance to next i (wave-uniform)
            ++i;
            if (i == SS - 1) { ++b; i = 0; }
            j = i + 1;
        }
    }
}

extern "C" void kernel_launch(void* const* d_in, const int* in_sizes, int n_in,
                              void* d_out, int out_size, void* d_ws, size_t ws_size,
                              hipStream_t stream) {
    const float* x    = (const float*)d_in[0];   // (8,160,256)
    const float* W    = (const float*)d_in[1];   // (512,256)
    const float* bias = (const float*)d_in[2];   // (256,)
    float* y   = (float*)d_ws;                   // ya[1280*256] then yb[1280*256]
    float* out = (float*)d_out;                  // (8,12720,256)

    dim3 gemm_grid(512 / 64, 1280 / 32);         // 8 x 40 = 320 blocks
    gemm_kernel<<<gemm_grid, 256, 0, stream>>>(x, W, bias, y);

    expand_kernel<<<NWAVES / 4, 256, 0, stream>>>(y, out);
}